// Round 1
// baseline (1437.304 us; speedup 1.0000x reference)
//
#include <hip/hip_runtime.h>

#define WW 64
#define CC 128
#define LDSROW 132   // 128 + 4-float pad: breaks power-of-2 row stride for LDS reads
#define SROW 65      // sims LDS row stride

__global__ __launch_bounds__(256, 2)
void fine_matching_kernel(const float* __restrict__ x0,
                          const float* __restrict__ x1,
                          float* __restrict__ out, int M) {
  __shared__ float x0p[WW * LDSROW];
  __shared__ float x1p[WW * LDSROW];
  __shared__ float m1s[WW], rZ1[WW], m2s[WW], rZ2[WW];
  __shared__ float redV[4];
  __shared__ int   redI[4];

  const int m = blockIdx.x;
  const int t = threadIdx.x;

  // ---- stage x0, x1 -> LDS (f32, padded rows), coalesced float4 ----
  const float4* g0 = (const float4*)(x0 + (size_t)m * (WW * CC));
  const float4* g1 = (const float4*)(x1 + (size_t)m * (WW * CC));
  #pragma unroll
  for (int i = 0; i < 8; ++i) {
    int q = t + 256 * i;        // float4 index within the 64x128 tile
    int row = q >> 5;           // 32 float4 per row
    int c4  = q & 31;
    float4 v0 = g0[q];
    float4 v1 = g1[q];
    *(float4*)&x0p[row * LDSROW + c4 * 4] = v0;
    *(float4*)&x1p[row * LDSROW + c4 * 4] = v1;
  }
  __syncthreads();

  // ---- sims: 4x4 register tile per thread, strided (l = r+16i, s = c+16j) ----
  const int r = t >> 4;   // 0..15
  const int c = t & 15;   // 0..15
  float acc[4][4];
  #pragma unroll
  for (int i = 0; i < 4; ++i)
    #pragma unroll
    for (int j = 0; j < 4; ++j) acc[i][j] = 0.f;

  #pragma unroll 2
  for (int kk = 0; kk < CC / 4; ++kk) {
    float4 a[4], b[4];
    #pragma unroll
    for (int i = 0; i < 4; ++i)
      a[i] = *(const float4*)&x0p[(r + 16 * i) * LDSROW + kk * 4];
    #pragma unroll
    for (int j = 0; j < 4; ++j)
      b[j] = *(const float4*)&x1p[(c + 16 * j) * LDSROW + kk * 4];
    #pragma unroll
    for (int i = 0; i < 4; ++i)
      #pragma unroll
      for (int j = 0; j < 4; ++j) {
        acc[i][j] = fmaf(a[i].x, b[j].x, acc[i][j]);
        acc[i][j] = fmaf(a[i].y, b[j].y, acc[i][j]);
        acc[i][j] = fmaf(a[i].z, b[j].z, acc[i][j]);
        acc[i][j] = fmaf(a[i].w, b[j].w, acc[i][j]);
      }
  }
  __syncthreads();   // all reads of x0p/x1p done; S aliases x0p below

  float* S = x0p;    // 64 x SROW sims buffer (4160 floats <= 8448)
  #pragma unroll
  for (int i = 0; i < 4; ++i)
    #pragma unroll
    for (int j = 0; j < 4; ++j)
      S[(r + 16 * i) * SROW + (c + 16 * j)] = acc[i][j] * (1.0f / 128.0f);
  __syncthreads();

  // ---- row stats: softmax over s for each l (axis=2) ----
  {
    int l = t >> 2, q = t & 3;
    const float* Sr = S + l * SROW + q * 16;
    float mx = -INFINITY;
    #pragma unroll
    for (int k = 0; k < 16; ++k) mx = fmaxf(mx, Sr[k]);
    mx = fmaxf(mx, __shfl_xor(mx, 1));
    mx = fmaxf(mx, __shfl_xor(mx, 2));
    float sm = 0.f;
    #pragma unroll
    for (int k = 0; k < 16; ++k) sm += __expf(Sr[k] - mx);
    sm += __shfl_xor(sm, 1);
    sm += __shfl_xor(sm, 2);
    if (q == 0) { m2s[l] = mx; rZ2[l] = 1.0f / sm; }
  }
  // ---- col stats: softmax over l for each s (axis=1) ----
  {
    int s = t >> 2, q = t & 3;
    float mx = -INFINITY;
    #pragma unroll
    for (int k = 0; k < 16; ++k) mx = fmaxf(mx, S[(q * 16 + k) * SROW + s]);
    mx = fmaxf(mx, __shfl_xor(mx, 1));
    mx = fmaxf(mx, __shfl_xor(mx, 2));
    float sm = 0.f;
    #pragma unroll
    for (int k = 0; k < 16; ++k) sm += __expf(S[(q * 16 + k) * SROW + s] - mx);
    sm += __shfl_xor(sm, 1);
    sm += __shfl_xor(sm, 2);
    if (q == 0) { m1s[s] = mx; rZ1[s] = 1.0f / sm; }
  }
  __syncthreads();

  // ---- heatmap write + masked argmax ----
  float bv = -INFINITY;
  int bi = 0x7fffffff;
  float* Hm = out + (size_t)m * 4096;
  #pragma unroll
  for (int k = 0; k < 16; ++k) {
    int fi = t + 256 * k;         // 0..4095, coalesced store
    int l = fi >> 6, s = fi & 63;
    float sv = S[l * SROW + s];
    float val = __expf(2.f * sv - m2s[l] - m1s[s]) * rZ2[l] * rZ1[s];
    Hm[fi] = val;
    bool ok = ((unsigned)((l >> 3) - 1) < 6u) && ((unsigned)((l & 7) - 1) < 6u)
           && ((unsigned)((s >> 3) - 1) < 6u) && ((unsigned)((s & 7) - 1) < 6u);
    if (ok && (val > bv || (val == bv && fi < bi))) { bv = val; bi = fi; }
  }
  // wave-level reduce (64 lanes), first-index tie-break
  #pragma unroll
  for (int off = 1; off < 64; off <<= 1) {
    float ov = __shfl_xor(bv, off);
    int oi = __shfl_xor(bi, off);
    if (ov > bv || (ov == bv && oi < bi)) { bv = ov; bi = oi; }
  }
  if ((t & 63) == 0) { redV[t >> 6] = bv; redI[t >> 6] = bi; }
  __syncthreads();
  if (t == 0) {
    float fbv = redV[0]; int fbi = redI[0];
    #pragma unroll
    for (int w = 1; w < 4; ++w) {
      if (redV[w] > fbv || (redV[w] == fbv && redI[w] < fbi)) { fbv = redV[w]; fbi = redI[w]; }
    }
    int l = fbi >> 6, s = fbi & 63;
    size_t H = (size_t)M * 4096;
    out[H + m]     = (float)l;           // idx_l
    out[H + M + m] = (float)s;           // idx_s
    float* b0 = out + H + 2 * (size_t)M; // biases0 (M,2)
    float* b1 = out + H + 4 * (size_t)M; // biases1 (M,2)
    b0[2 * m]     = (float)(l & 7) - 3.5f;
    b0[2 * m + 1] = (float)(l >> 3) - 3.5f;
    b1[2 * m]     = (float)(s & 7) - 3.5f;
    b1[2 * m + 1] = (float)(s >> 3) - 3.5f;
  }
}

extern "C" void kernel_launch(void* const* d_in, const int* in_sizes, int n_in,
                              void* d_out, int out_size, void* d_ws, size_t ws_size,
                              hipStream_t stream) {
  const float* x0 = (const float*)d_in[0];
  const float* x1 = (const float*)d_in[1];
  float* out = (float*)d_out;
  int M = in_sizes[0] / (WW * CC);
  fine_matching_kernel<<<M, 256, 0, stream>>>(x0, x1, out, M);
}